// Round 5
// baseline (5788.870 us; speedup 1.0000x reference)
//
#include <hip/hip_runtime.h>
#include <math.h>

#define Bn   16
#define TINn 112
#define Tn   28
#define NPIX (Bn * Tn * 256)   // 114688 pixels, each [b,t,h,w]

typedef float f32x4  __attribute__((ext_vector_type(4)));
typedef short bf16x8 __attribute__((ext_vector_type(8)));

__device__ __forceinline__ ushort f2bf(float v) {
    uint u = __float_as_uint(v);
    return (ushort)((u + 0x7fffu + ((u >> 16) & 1u)) >> 16);   // RNE
}
__device__ __forceinline__ float bf2f(ushort u) { return __uint_as_float((uint)u << 16); }

__device__ __forceinline__ void  stz(float* p, float v)  { *p = v; }
__device__ __forceinline__ void  stz(ushort* p, float v) { *p = f2bf(v); }
__device__ __forceinline__ float ldz(const float* p)     { return *p; }
__device__ __forceinline__ float ldz(const ushort* p)    { return bf2f(*p); }

// ---------------- embed: x[B,112,16,16,6] -> xecat[pix][64] = [hi24|lo24|0pad16] ----------------
__global__ void embed3(const float* __restrict__ x, ushort* __restrict__ xe) {
    int p = blockIdx.x * 256 + threadIdx.x;
    if (p >= NPIX) return;
    int w = p & 15, h = (p >> 4) & 15, t = (p >> 8) % Tn, b = p / (Tn * 256);
    ushort buf[64];
    #pragma unroll
    for (int j = 0; j < 4; ++j) {
        const float* src = x + ((((size_t)b * TINn + t * 4 + j) * 16 + h) * 16 + w) * 6;
        #pragma unroll
        for (int ci = 0; ci < 6; ++ci) {
            float v = src[ci];
            ushort hi = f2bf(v);
            buf[j * 6 + ci] = hi;
            buf[24 + j * 6 + ci] = f2bf(v - bf2f(hi));
        }
    }
    #pragma unroll
    for (int k = 48; k < 64; ++k) buf[k] = 0;
    uint4* dst = (uint4*)(xe + (size_t)p * 64);
    const uint4* s4 = (const uint4*)buf;
    #pragma unroll
    for (int i = 0; i < 8; ++i) dst[i] = s4[i];
}

// ---------------- weight prep: fp32 [9][K][256] -> bf16 [n=256][9*TKP], k<K real, dup copies, rest 0 ----------------
__global__ void prep_wT(const float* __restrict__ src, ushort* __restrict__ dst,
                        int K, int TKP, int dup) {
    int i = blockIdx.x * 256 + threadIdx.x;
    int tot = 256 * 9 * TKP;
    if (i >= tot) return;
    int rem = i % (9 * TKP);
    int n = i / (9 * TKP);
    int tap = rem / TKP;
    int k = rem % TKP;
    float v = 0.f;
    if (k < K)                 v = src[((size_t)tap * K + k) * 256 + n];
    else if (dup && k < 2 * K) v = src[((size_t)tap * K + (k - K)) * 256 + n];
    dst[i] = f2bf(v);
}

// ---------------- xz GEMM: Z[pix][512] = im2col(A) * W^T + bias ----------------
// A: [pix][AS] contiguous K-strip per tap (AS = 64 for xe, 256 for h0cat)
// W: per dir [256][9*AS]. grid: x = pix/128 tiles, y = 0..3 (dir = y>>1, n-half = y&1)
template<typename ZT>
__global__ __launch_bounds__(256)
void xz_gemm(const ushort* __restrict__ A,
             const ushort* __restrict__ Wf, const ushort* __restrict__ Wb,
             const float* __restrict__ biasf, const float* __restrict__ biasb,
             ZT* __restrict__ Z, int AS, int CPT) {
    __shared__ __align__(16) ushort As[2][128][72];
    __shared__ __align__(16) ushort Bs[2][128][72];

    const int tid = threadIdx.x;
    const int Mbase = blockIdx.x * 128;
    const int dir = blockIdx.y >> 1, nh = blockIdx.y & 1;
    const ushort* W = dir ? Wb : Wf;
    const float* bias = dir ? biasb : biasf;
    const int imgbase = (Mbase >> 8) << 8;
    const int local = Mbase & 255;
    const int WK = 9 * AS;

    const int srow = tid >> 1, sk0 = (tid & 1) * 32;
    const int lane = tid & 63, wv = tid >> 6;
    const int wr = wv >> 1, wc = wv & 1;
    const int fr = lane & 15, kg = lane >> 4;

    const int nchunks = 9 * CPT;
    uint4 ra[4], rb[4];
    auto issue = [&](int c) {
        int tap = c / CPT, ko = (c % CPT) * 64;
        int dh = tap / 3 - 1, dw = tap % 3 - 1;
        int hh = ((local + srow) >> 4) + dh;
        int ww = (srow & 15) + dw;
        bool v = ((unsigned)hh < 16u) && ((unsigned)ww < 16u);
        const uint4* asrc = (const uint4*)(A + (size_t)(imgbase + hh * 16 + ww) * AS + ko + sk0);
        uint4 zz = make_uint4(0, 0, 0, 0);
        #pragma unroll
        for (int i = 0; i < 4; ++i) ra[i] = v ? asrc[i] : zz;
        const uint4* bsrc = (const uint4*)(W + (size_t)(nh * 128 + srow) * WK + tap * AS + ko + sk0);
        #pragma unroll
        for (int i = 0; i < 4; ++i) rb[i] = bsrc[i];
    };
    auto commit = [&](int buf) {
        uint4* ad = (uint4*)&As[buf][srow][sk0];
        #pragma unroll
        for (int i = 0; i < 4; ++i) ad[i] = ra[i];
        uint4* bd = (uint4*)&Bs[buf][srow][sk0];
        #pragma unroll
        for (int i = 0; i < 4; ++i) bd[i] = rb[i];
    };

    f32x4 acc[4][4] = {};
    auto compute = [&](int buf) {
        #pragma unroll
        for (int s = 0; s < 2; ++s) {
            bf16x8 a[4], b[4];
            #pragma unroll
            for (int i = 0; i < 4; ++i) {
                a[i] = *(const bf16x8*)&As[buf][wr * 64 + i * 16 + fr][s * 32 + kg * 8];
                b[i] = *(const bf16x8*)&Bs[buf][wc * 64 + i * 16 + fr][s * 32 + kg * 8];
            }
            #pragma unroll
            for (int mi = 0; mi < 4; ++mi)
                #pragma unroll
                for (int ni = 0; ni < 4; ++ni)
                    acc[mi][ni] = __builtin_amdgcn_mfma_f32_16x16x32_bf16(a[mi], b[ni], acc[mi][ni], 0, 0, 0);
        }
    };

    issue(0); commit(0); __syncthreads();
    for (int c = 0; c < nchunks; ++c) {
        int buf = c & 1;
        if (c + 1 < nchunks) issue(c + 1);
        compute(buf);
        if (c + 1 < nchunks) commit(buf ^ 1);
        __syncthreads();
    }

    float bv[4];
    #pragma unroll
    for (int ni = 0; ni < 4; ++ni) bv[ni] = bias[nh * 128 + wc * 64 + ni * 16 + fr];
    #pragma unroll
    for (int mi = 0; mi < 4; ++mi)
        #pragma unroll
        for (int ni = 0; ni < 4; ++ni)
            #pragma unroll
            for (int r = 0; r < 4; ++r) {
                int pix = Mbase + wr * 64 + mi * 16 + kg * 4 + r;
                int n = nh * 128 + wc * 64 + ni * 16 + fr;
                stz(Z + (size_t)pix * 512 + dir * 256 + n, acc[mi][ni][r] + bv[ni]);
            }
}

// ---------------- recurrent step: z-init + h2h MFMA + gates ----------------
// zin [pix][512] (bias baked). hbuf doubles as recurrent input (prev t slot) and output.
// PASSES=2: l0 (h0cat [pix][256] hi|lo, astride 256); PASSES=1: l1 (h1 [pix][128], astride 128)
template<int PASSES, typename ZT>
__global__ __launch_bounds__(256)
void lstm_step2(const ZT* __restrict__ zin,
                const ushort* __restrict__ Whf, const ushort* __restrict__ Whb,
                ushort* __restrict__ hbuf, float* __restrict__ c_ws,
                int t, int astride) {
    __shared__ __align__(16) ushort Bs[2][256][72];
    __shared__ __align__(16) ushort As[2][16][72];
    float* Zs = (float*)&Bs[0][0][0];   // [256][17], used after compute

    const int tid = threadIdx.x;
    const int dir = blockIdx.y;
    const int b = blockIdx.x >> 4, h = blockIdx.x & 15;
    const int t_orig = dir ? (Tn - 1 - t) : t;
    const ushort* Wh = dir ? Whb : Whf;

    const int lane = tid & 63, wv = tid >> 6;
    const int fr = lane & 15, kg = lane >> 4;

    f32x4 acc[4];
    {
        const size_t zrow = (size_t)(b * Tn + t_orig) * 256 + h * 16;
        #pragma unroll
        for (int q = 0; q < 4; ++q)
            #pragma unroll
            for (int r = 0; r < 4; ++r)
                acc[q][r] = ldz(zin + (zrow + kg * 4 + r) * 512 + dir * 256 + wv * 64 + q * 16 + fr);
    }

    if (t > 0) {
        const int tp = t_orig + (dir ? 1 : -1);
        const int kh0 = (h == 0) ? 1 : 0;
        const int khn = ((h == 15) ? 2 : 3) - kh0;
        const int nchunks = khn * 3 * PASSES;
        const int arow_ = tid >> 3, aj = tid & 7;

        uint4 rb[8], raa;
        auto issue = [&](int c) {
            int tap = c / PASSES, pass = c % PASSES;
            int kh = kh0 + tap / 3, kw = tap % 3;
            int tapidx = kh * 3 + kw, dw = kw - 1;
            const uint4* bsrc = (const uint4*)(Wh + (size_t)tid * 576 + tapidx * 64);
            #pragma unroll
            for (int i = 0; i < 8; ++i) rb[i] = bsrc[i];
            raa = make_uint4(0, 0, 0, 0);
            if (tid < 128) {
                int ww = arow_ + dw;
                if ((unsigned)ww < 16u) {
                    int aoff = (PASSES == 2) ? (pass ? 128 + dir * 64 : dir * 64) : dir * 64;
                    const ushort* asrc = hbuf
                        + ((size_t)((b * Tn + tp) * 16 + (h + kh - 1)) * 16 + ww) * astride
                        + aoff + aj * 8;
                    raa = *(const uint4*)asrc;
                }
            }
        };
        auto commit = [&](int buf) {
            uint4* bd = (uint4*)&Bs[buf][tid][0];
            #pragma unroll
            for (int i = 0; i < 8; ++i) bd[i] = rb[i];
            if (tid < 128) *(uint4*)&As[buf][arow_][aj * 8] = raa;
        };
        auto compute = [&](int buf) {
            #pragma unroll
            for (int s = 0; s < 2; ++s) {
                bf16x8 a = *(const bf16x8*)&As[buf][fr][s * 32 + kg * 8];
                #pragma unroll
                for (int q = 0; q < 4; ++q) {
                    bf16x8 bq = *(const bf16x8*)&Bs[buf][wv * 64 + q * 16 + fr][s * 32 + kg * 8];
                    acc[q] = __builtin_amdgcn_mfma_f32_16x16x32_bf16(a, bq, acc[q], 0, 0, 0);
                }
            }
        };

        issue(0); commit(0); __syncthreads();
        for (int c = 0; c < nchunks; ++c) {
            int buf = c & 1;
            if (c + 1 < nchunks) issue(c + 1);
            compute(buf);
            if (c + 1 < nchunks) commit(buf ^ 1);
            __syncthreads();
        }
    } else {
        __syncthreads();   // uniform arrival before LDS reuse
    }

    // exchange z via Zs (aliases Bs[0]; all compute done)
    #pragma unroll
    for (int q = 0; q < 4; ++q)
        #pragma unroll
        for (int r = 0; r < 4; ++r)
            Zs[(wv * 64 + q * 16 + fr) * 17 + kg * 4 + r] = acc[q][r];
    __syncthreads();

    const int m = tid >> 4, f0 = (tid & 15) << 2;
    float zz[4][4];
    #pragma unroll
    for (int g = 0; g < 4; ++g)
        #pragma unroll
        for (int i = 0; i < 4; ++i)
            zz[g][i] = Zs[((g << 6) + f0 + i) * 17 + m];

    float* cp = c_ws + ((size_t)((dir * 16 + b) * 256) + (h << 4) + m) * 64 + f0;
    float cov[4] = {0.f, 0.f, 0.f, 0.f};
    if (t > 0) {
        float4 c4 = *(const float4*)cp;
        cov[0] = c4.x; cov[1] = c4.y; cov[2] = c4.z; cov[3] = c4.w;
    }
    float cn[4], hn[4];
    #pragma unroll
    for (int i = 0; i < 4; ++i) {
        float gi = 1.f / (1.f + expf(-zz[0][i]));
        float gf = 1.f / (1.f + expf(-zz[1][i]));
        float gg = tanhf(zz[2][i]);
        float go = 1.f / (1.f + expf(-zz[3][i]));
        float c = gf * cov[i] + gi * gg;
        cn[i] = c; hn[i] = go * tanhf(c);
    }
    *(float4*)cp = make_float4(cn[0], cn[1], cn[2], cn[3]);

    const size_t pix = (size_t)(b * Tn + t_orig) * 256 + (h << 4) + m;
    ushort4 hhi;
    hhi.x = f2bf(hn[0]); hhi.y = f2bf(hn[1]); hhi.z = f2bf(hn[2]); hhi.w = f2bf(hn[3]);
    *(ushort4*)&hbuf[pix * astride + dir * 64 + f0] = hhi;
    if (PASSES == 2) {
        ushort4 hlo;
        hlo.x = f2bf(hn[0] - bf2f(hhi.x)); hlo.y = f2bf(hn[1] - bf2f(hhi.y));
        hlo.z = f2bf(hn[2] - bf2f(hhi.z)); hlo.w = f2bf(hn[3] - bf2f(hhi.w));
        *(ushort4*)&hbuf[pix * astride + 128 + dir * 64 + f0] = hlo;
    }
}

// ---------------- final TimeDistributed Conv2D: h1 bf16 [pix][128] -> out fp32 ----------------
__global__ void out_conv(const ushort* __restrict__ h1,
                         const float* __restrict__ wout,
                         const float* __restrict__ bout,
                         float* __restrict__ out) {
    int idx = blockIdx.x * 256 + threadIdx.x;
    if (idx >= NPIX) return;
    int w = idx & 15;
    int h = (idx >> 4) & 15;
    int r = idx >> 8;
    int t = r % Tn;
    int b = r / Tn;

    float acc = bout[0];
    for (int kh = 0; kh < 3; ++kh) {
        int hh = h + kh - 1;
        if ((unsigned)hh >= 16u) continue;
        for (int kw = 0; kw < 3; ++kw) {
            int ww = w + kw - 1;
            if ((unsigned)ww >= 16u) continue;
            const ushort* hp = h1 + ((size_t)(b * Tn + t) * 256 + hh * 16 + ww) * 128;
            const float* wp = wout + (kh * 3 + kw) * 128;
            #pragma unroll 4
            for (int v = 0; v < 16; ++v) {
                uint4 q = *(const uint4*)(hp + v * 8);
                acc = fmaf(bf2f((ushort)(q.x & 0xffff)), wp[v * 8 + 0], acc);
                acc = fmaf(bf2f((ushort)(q.x >> 16)),    wp[v * 8 + 1], acc);
                acc = fmaf(bf2f((ushort)(q.y & 0xffff)), wp[v * 8 + 2], acc);
                acc = fmaf(bf2f((ushort)(q.y >> 16)),    wp[v * 8 + 3], acc);
                acc = fmaf(bf2f((ushort)(q.z & 0xffff)), wp[v * 8 + 4], acc);
                acc = fmaf(bf2f((ushort)(q.z >> 16)),    wp[v * 8 + 5], acc);
                acc = fmaf(bf2f((ushort)(q.w & 0xffff)), wp[v * 8 + 6], acc);
                acc = fmaf(bf2f((ushort)(q.w >> 16)),    wp[v * 8 + 7], acc);
            }
        }
    }
    out[idx] = acc;
}

extern "C" void kernel_launch(void* const* d_in, const int* in_sizes, int n_in,
                              void* d_out, int out_size, void* d_ws, size_t ws_size,
                              hipStream_t stream) {
    const float* x    = (const float*)d_in[0];
    const float* wx0f = (const float*)d_in[1];
    const float* wh0f = (const float*)d_in[2];
    const float* b0f  = (const float*)d_in[3];
    const float* wx0b = (const float*)d_in[4];
    const float* wh0b = (const float*)d_in[5];
    const float* b0b  = (const float*)d_in[6];
    const float* wx1f = (const float*)d_in[7];
    const float* wh1f = (const float*)d_in[8];
    const float* b1f  = (const float*)d_in[9];
    const float* wx1b = (const float*)d_in[10];
    const float* wh1b = (const float*)d_in[11];
    const float* b1b  = (const float*)d_in[12];
    const float* wout = (const float*)d_in[13];
    const float* bout = (const float*)d_in[14];
    float* out = (float*)d_out;
    (void)in_sizes; (void)n_in; (void)out_size;

    size_t off = 0;
    auto alloc = [&](size_t bytes) {
        void* p = (char*)d_ws + off;
        off += (bytes + 255) & ~(size_t)255;
        return p;
    };

    const size_t XZ_F32 = (size_t)NPIX * 512 * 4;      // 234.9 MB
    const size_t XZ_BF  = (size_t)NPIX * 512 * 2;      // 117.4 MB
    const size_t FIXED  = (size_t)NPIX * 64 * 2        // xecat
                        + (size_t)NPIX * 256 * 2       // h0cat
                        + (size_t)NPIX * 128 * 2       // h1
                        + 2 * (256 * 576 * 2)          // wx0T
                        + 2 * ((size_t)256 * 2304 * 2) // wx1T
                        + 4 * (256 * 576 * 2)          // wh0T, wh1T
                        + (size_t)2 * 16 * 256 * 64 * 4 // cws
                        + 16 * 256;                    // align slack
    const bool zf32 = ws_size >= FIXED + XZ_F32;

    void*   xz    = alloc(zf32 ? XZ_F32 : XZ_BF);
    ushort* xecat = (ushort*)alloc((size_t)NPIX * 64 * 2);
    ushort* h0cat = (ushort*)alloc((size_t)NPIX * 256 * 2);
    ushort* h1    = (ushort*)alloc((size_t)NPIX * 128 * 2);
    ushort* wx0fT = (ushort*)alloc(256 * 576 * 2);
    ushort* wx0bT = (ushort*)alloc(256 * 576 * 2);
    ushort* wx1fT = (ushort*)alloc((size_t)256 * 2304 * 2);
    ushort* wx1bT = (ushort*)alloc((size_t)256 * 2304 * 2);
    ushort* wh0fT = (ushort*)alloc(256 * 576 * 2);
    ushort* wh0bT = (ushort*)alloc(256 * 576 * 2);
    ushort* wh1fT = (ushort*)alloc(256 * 576 * 2);
    ushort* wh1bT = (ushort*)alloc(256 * 576 * 2);
    float*  cws   = (float*)alloc((size_t)2 * 16 * 256 * 64 * 4);

    // weight repack
    prep_wT<<<(256 * 9 * 64  + 255) / 256, 256, 0, stream>>>(wx0f, wx0fT, 24, 64, 1);
    prep_wT<<<(256 * 9 * 64  + 255) / 256, 256, 0, stream>>>(wx0b, wx0bT, 24, 64, 1);
    prep_wT<<<(256 * 9 * 256 + 255) / 256, 256, 0, stream>>>(wx1f, wx1fT, 128, 256, 1);
    prep_wT<<<(256 * 9 * 256 + 255) / 256, 256, 0, stream>>>(wx1b, wx1bT, 128, 256, 1);
    prep_wT<<<(256 * 9 * 64  + 255) / 256, 256, 0, stream>>>(wh0f, wh0fT, 64, 64, 0);
    prep_wT<<<(256 * 9 * 64  + 255) / 256, 256, 0, stream>>>(wh0b, wh0bT, 64, 64, 0);
    prep_wT<<<(256 * 9 * 64  + 255) / 256, 256, 0, stream>>>(wh1f, wh1fT, 64, 64, 0);
    prep_wT<<<(256 * 9 * 64  + 255) / 256, 256, 0, stream>>>(wh1b, wh1bT, 64, 64, 0);

    embed3<<<(NPIX + 255) / 256, 256, 0, stream>>>(x, xecat);

    const dim3 ggrid(NPIX / 128, 4), sgrid(256, 2);
    if (zf32) {
        float* z = (float*)xz;
        xz_gemm<float><<<ggrid, 256, 0, stream>>>(xecat, wx0fT, wx0bT, b0f, b0b, z, 64, 1);
        for (int t = 0; t < Tn; ++t)
            lstm_step2<2, float><<<sgrid, 256, 0, stream>>>(z, wh0fT, wh0bT, h0cat, cws, t, 256);
        xz_gemm<float><<<ggrid, 256, 0, stream>>>(h0cat, wx1fT, wx1bT, b1f, b1b, z, 256, 4);
        for (int t = 0; t < Tn; ++t)
            lstm_step2<1, float><<<sgrid, 256, 0, stream>>>(z, wh1fT, wh1bT, h1, cws, t, 128);
    } else {
        ushort* z = (ushort*)xz;
        xz_gemm<ushort><<<ggrid, 256, 0, stream>>>(xecat, wx0fT, wx0bT, b0f, b0b, z, 64, 1);
        for (int t = 0; t < Tn; ++t)
            lstm_step2<2, ushort><<<sgrid, 256, 0, stream>>>(z, wh0fT, wh0bT, h0cat, cws, t, 256);
        xz_gemm<ushort><<<ggrid, 256, 0, stream>>>(h0cat, wx1fT, wx1bT, b1f, b1b, z, 256, 4);
        for (int t = 0; t < Tn; ++t)
            lstm_step2<1, ushort><<<sgrid, 256, 0, stream>>>(z, wh1fT, wh1bT, h1, cws, t, 128);
    }

    out_conv<<<(NPIX + 255) / 256, 256, 0, stream>>>(h1, wout, bout, out);
}